// Round 7
// baseline (3576.820 us; speedup 1.0000x reference)
//
#include <hip/hip_runtime.h>
#include <math.h>

#define S_LEN 4096
#define D_DIM 768
#define M_CNT 1024
#define K_CNT 32
#define MK_CNT 32768
#define DH_DIM 96
#define CTX_W 10

typedef __bf16 bf16_t;
typedef bf16_t bf16x8 __attribute__((ext_vector_type(8)));
typedef float f32x4 __attribute__((ext_vector_type(4)));
typedef float f32x16 __attribute__((ext_vector_type(16)));
typedef int i32x4 __attribute__((ext_vector_type(4)));
typedef int i32x8 __attribute__((ext_vector_type(8)));

// ---------------------------------------------------------------- reduces
__device__ __forceinline__ float block_reduce_sum(float v, float* sbuf) {
#pragma unroll
    for (int off = 32; off; off >>= 1) v += __shfl_down(v, off);
    __syncthreads();
    int wave = threadIdx.x >> 6;
    int lane = threadIdx.x & 63;
    if (lane == 0) sbuf[wave] = v;
    __syncthreads();
    return sbuf[0] + sbuf[1] + sbuf[2] + sbuf[3];
}

__device__ __forceinline__ float wave_sum(float v) {
#pragma unroll
    for (int off = 32; off; off >>= 1) v += __shfl_down(v, off);
    return __shfl(v, 0);
}

__device__ __forceinline__ unsigned char to_fp8(float v) {
    return (unsigned char)(__builtin_amdgcn_cvt_pk_fp8_f32(v, v, 0, false) & 0xff);
}

__device__ __forceinline__ void ld2(const bf16_t* p, float& a, float& b) {
    ushort2 u = *(const ushort2*)p;
    a = __uint_as_float((unsigned)u.x << 16);
    b = __uint_as_float((unsigned)u.y << 16);
}

// ---------------------------------------------------------------- bf16 MFMA GEMM (128x128 tile)
template<int OUT_BF16, int RELU>
__global__ __launch_bounds__(256, 2) void gemm_mfma(
    const bf16_t* __restrict__ A, const bf16_t* __restrict__ Bt,
    const float* __restrict__ bias, void* __restrict__ C,
    int Kd, int N, int nx, int ny)
{
    __shared__ bf16_t As[128 * 64];
    __shared__ bf16_t Bs[128 * 64];
    const int tid = threadIdx.x;
    const int w = tid >> 6, l = tid & 63;
    int per = 8 * nx;
    int g = blockIdx.x / per, rr = blockIdx.x % per;
    int gs = ny - g * 8; if (gs > 8) gs = 8;
    const int row0 = (g * 8 + rr % gs) * 128, col0 = (rr / gs) * 128;

    const int srow = w * 8 + (l >> 3);
    const int gchunk = (l & 7) ^ ((l >> 3) & 7);
    const bf16_t* gA = A + (size_t)(row0 + srow) * Kd + gchunk * 8;
    const bf16_t* gB = Bt + (size_t)(col0 + srow) * Kd + gchunk * 8;

    const int wm = w >> 1, wn = w & 1;
    f32x4 acc[4][4] = {};

    for (int k0 = 0; k0 < Kd; k0 += 64) {
#pragma unroll
        for (int c = 0; c < 4; ++c) {
            __builtin_amdgcn_global_load_lds(
                (const __attribute__((address_space(1))) void*)(gA + (size_t)(c * 32) * Kd + k0),
                (__attribute__((address_space(3))) void*)(As + (c * 256 + w * 64) * 8), 16, 0, 0);
            __builtin_amdgcn_global_load_lds(
                (const __attribute__((address_space(1))) void*)(gB + (size_t)(c * 32) * Kd + k0),
                (__attribute__((address_space(3))) void*)(Bs + (c * 256 + w * 64) * 8), 16, 0, 0);
        }
        __syncthreads();
#pragma unroll
        for (int ks = 0; ks < 2; ++ks) {
            bf16x8 af[4], bfr[4];
#pragma unroll
            for (int i = 0; i < 4; ++i) {
                int arow = wm * 64 + i * 16 + (l & 15);
                int slot = (ks * 4 + (l >> 4)) ^ (l & 7);
                af[i] = *(const bf16x8*)(As + arow * 64 + slot * 8);
                int brow = wn * 64 + i * 16 + (l & 15);
                bfr[i] = *(const bf16x8*)(Bs + brow * 64 + slot * 8);
            }
#pragma unroll
            for (int i = 0; i < 4; ++i)
#pragma unroll
                for (int j = 0; j < 4; ++j)
                    acc[i][j] = __builtin_amdgcn_mfma_f32_16x16x32_bf16(af[i], bfr[j], acc[i][j], 0, 0, 0);
        }
        __syncthreads();
    }

#pragma unroll
    for (int i = 0; i < 4; ++i) {
        int row = row0 + wm * 64 + i * 16 + (l >> 4) * 4;
#pragma unroll
        for (int j = 0; j < 4; ++j) {
            int col = col0 + wn * 64 + j * 16 + (l & 15);
            float bv = bias ? bias[col] : 0.f;
#pragma unroll
            for (int r = 0; r < 4; ++r) {
                float v = acc[i][j][r] + bv;
                if (RELU) v = fmaxf(v, 0.f);
                if (OUT_BF16) ((bf16_t*)C)[(size_t)(row + r) * N + col] = (bf16_t)v;
                else          ((float*)C)[(size_t)(row + r) * N + col] = v;
            }
        }
    }
}

static inline void launch_gemm(const bf16_t* A, const bf16_t* Bt, const float* bias, void* C,
                               int rows, int Kd, int N, bool relu, bool outbf, hipStream_t st) {
    int nx = N / 128, ny = rows / 128;
    dim3 grid(nx * ny);
    if (outbf) {
        if (relu) gemm_mfma<1, 1><<<grid, 256, 0, st>>>(A, Bt, bias, C, Kd, N, nx, ny);
        else      gemm_mfma<1, 0><<<grid, 256, 0, st>>>(A, Bt, bias, C, Kd, N, nx, ny);
    } else {
        if (relu) gemm_mfma<0, 1><<<grid, 256, 0, st>>>(A, Bt, bias, C, Kd, N, nx, ny);
        else      gemm_mfma<0, 0><<<grid, 256, 0, st>>>(A, Bt, bias, C, Kd, N, nx, ny);
    }
}

// ---------------------------------------------------------------- fp8 MX-MFMA GEMM
// Fine-phase (T3+T4) structure: 256x256 tile, 8 waves (2x4), per-wave 128x64
// (acc[4][2], R6 layout). A-only LDS, FOUR-buffer ring (128 KB), stage depth 2.
// Per K-tile(128): 4 phases {stage 1 chunk of kt+2 | (p0: prefetch B(kt+1) to
// VGPR from packed layout) | 4 ds_read | pacing barrier | setprio+4 MFMA}.
// Counted s_waitcnt vmcnt(4) ONCE per kt-top, never 0 in main loop.
// Ledger: at kt top outstanding = [B(kt) x8, A(kt+1) x4] -> vmcnt(4) keeps
// exactly A(kt+1). WAR on buf (kt+2)&3 closed by kt-top barrier (last read
// was kt-2, all reads complete before any wave passes kt-1's top barrier).
// B double-buffered in NAMED i32x8 regs (even kt: bA, odd kt: bB).
// OMODE: 0=f32, 1=fp8, 2=bf16. RESID: add bf16 residual before store.
template<int OMODE, int RELU, int RESID>
__global__ __launch_bounds__(512, 2) void gemm_fp8(
    const unsigned char* __restrict__ A, const unsigned char* __restrict__ Bp,
    const float* __restrict__ bias, void* __restrict__ C,
    const bf16_t* __restrict__ resid,
    int Kd, int N, int nx, int ny)
{
    __shared__ unsigned char As[4 * 256 * 128];
    const int tid = threadIdx.x;
    const int w = tid >> 6, l = tid & 63;
    int per = 8 * nx;
    int g = blockIdx.x / per, rrb = blockIdx.x % per;
    int gs = ny - g * 8; if (gs > 8) gs = 8;
    const int row0 = (g * 8 + rrb % gs) * 256, col0 = (rrb / gs) * 256;
    const int wm = w >> 2, wn = w & 3;
    const int SA = 0x7F7F7F7F;          // E8M0 scale = 1.0 in every byte
    const int KT = Kd >> 7;             // K-tiles of 128 (6 or 24 - always even)

    // A staging: 512 thr x 16B = 8 KB = 64 rows per call; thread t -> row t>>3,
    // slot t&7; pre-swizzled source chunk (t&7)^((t>>3)&7) so LDS slot s of
    // row r holds chunk s^(r&7) (verified R2/R6 invariant).
    const int gch = (tid & 7) ^ ((tid >> 3) & 7);
    const unsigned char* gA = A + (size_t)(row0 + (tid >> 3)) * Kd + gch * 16;

    // packed-B per-lane base (verified R6): P[cg][kt][s][half][chunk][col][16B]
    const int cg0 = (col0 >> 5) + wn * 2;
    const unsigned char* gB0 = Bp + (size_t)cg0 * KT * 4096 + (l >> 5) * 1024 + (l & 31) * 16;
    const unsigned char* gB1 = gB0 + (size_t)KT * 4096;

    f32x16 acc[4][2] = {};
    i32x8 bA0, bA1, bA2, bA3, bB0, bB1, bB2, bB3;   // [j0s0, j0s1, j1s0, j1s1]

    auto stageA = [&](int buf, int ktv, int c) {
        __builtin_amdgcn_global_load_lds(
            (const __attribute__((address_space(1))) void*)(gA + (size_t)(c * 64) * Kd + ktv * 128),
            (__attribute__((address_space(3))) void*)(As + buf * 32768 + c * 8192 + w * 1024), 16, 0, 0);
    };

#define LOADB8(b0v, b1v, b2v, b3v, ktv)                                         \
    {   const unsigned char* p0_ = gB0 + (size_t)(ktv) * 4096;                  \
        const unsigned char* p1_ = gB1 + (size_t)(ktv) * 4096;                  \
        i32x4 q0 = *(const i32x4*)(p0_),        q1 = *(const i32x4*)(p0_ + 512);\
        i32x4 q2 = *(const i32x4*)(p0_ + 2048), q3 = *(const i32x4*)(p0_ + 2560);\
        i32x4 q4 = *(const i32x4*)(p1_),        q5 = *(const i32x4*)(p1_ + 512);\
        i32x4 q6 = *(const i32x4*)(p1_ + 2048), q7 = *(const i32x4*)(p1_ + 2560);\
        b0v = (i32x8){q0[0],q0[1],q0[2],q0[3],q1[0],q1[1],q1[2],q1[3]};         \
        b1v = (i32x8){q2[0],q2[1],q2[2],q2[3],q3[0],q3[1],q3[2],q3[3]};         \
        b2v = (i32x8){q4[0],q4[1],q4[2],q4[3],q5[0],q5[1],q5[2],q5[3]};         \
        b3v = (i32x8){q6[0],q6[1],q6[2],q6[3],q7[0],q7[1],q7[2],q7[3]};         }

#define KT_STEP(T, BU0, BU1, BU2, BU3, BP0, BP1, BP2, BP3, DO_PRE, DO_STAGE, VMS) \
    {   asm volatile("s_waitcnt vmcnt(" VMS ")" ::: "memory");                  \
        __builtin_amdgcn_s_barrier();                                           \
        __builtin_amdgcn_sched_barrier(0);                                      \
        const unsigned char* as_ = As + ((T) & 3) * 32768;                      \
        _Pragma("unroll")                                                       \
        for (int p = 0; p < 4; ++p) {                                           \
            if (p == 0 && (DO_PRE)) LOADB8(BP0, BP1, BP2, BP3, (T) + 1);        \
            if (DO_STAGE) stageA(((T) + 2) & 3, (T) + 2, p);                    \
            int row_ = wm * 128 + p * 32 + (l & 31);                            \
            int c0_ = (l >> 5) << 1;                                            \
            i32x4 a0l = *(const i32x4*)(as_ + row_ * 128 + (((c0_    )) ^ (row_ & 7)) * 16); \
            i32x4 a0h = *(const i32x4*)(as_ + row_ * 128 + (((c0_ + 1)) ^ (row_ & 7)) * 16); \
            i32x4 a1l = *(const i32x4*)(as_ + row_ * 128 + (((c0_ + 4)) ^ (row_ & 7)) * 16); \
            i32x4 a1h = *(const i32x4*)(as_ + row_ * 128 + (((c0_ + 5)) ^ (row_ & 7)) * 16); \
            __builtin_amdgcn_s_barrier();                                       \
            __builtin_amdgcn_sched_barrier(0);                                  \
            i32x8 af0 = (i32x8){a0l[0],a0l[1],a0l[2],a0l[3],a0h[0],a0h[1],a0h[2],a0h[3]}; \
            i32x8 af1 = (i32x8){a1l[0],a1l[1],a1l[2],a1l[3],a1h[0],a1h[1],a1h[2],a1h[3]}; \
            __builtin_amdgcn_s_setprio(1);                                      \
            acc[p][0] = __builtin_amdgcn_mfma_scale_f32_32x32x64_f8f6f4(af0, BU0, acc[p][0], 0, 0, 0, SA, 0, SA); \
            acc[p][0] = __builtin_amdgcn_mfma_scale_f32_32x32x64_f8f6f4(af1, BU1, acc[p][0], 0, 0, 0, SA, 0, SA); \
            acc[p][1] = __builtin_amdgcn_mfma_scale_f32_32x32x64_f8f6f4(af0, BU2, acc[p][1], 0, 0, 0, SA, 0, SA); \
            acc[p][1] = __builtin_amdgcn_mfma_scale_f32_32x32x64_f8f6f4(af1, BU3, acc[p][1], 0, 0, 0, SA, 0, SA); \
            __builtin_amdgcn_s_setprio(0);                                      \
            __builtin_amdgcn_sched_barrier(0);                                  \
        }                                                                       }

    // prologue: B(0); A(0)->buf0; A(1)->buf1  (outstanding: 8+4+4=16)
    LOADB8(bA0, bA1, bA2, bA3, 0);
#pragma unroll
    for (int c = 0; c < 4; ++c) stageA(0, 0, c);
#pragma unroll
    for (int c = 0; c < 4; ++c) stageA(1, 1, c);

    int t = 0;
    for (; t + 2 < KT; t += 2) {
        KT_STEP(t,     bA0,bA1,bA2,bA3, bB0,bB1,bB2,bB3, 1, 1, "4");
        KT_STEP(t + 1, bB0,bB1,bB2,bB3, bA0,bA1,bA2,bA3, 1, (t + 3) < KT, "4");
    }
    KT_STEP(KT - 2, bA0,bA1,bA2,bA3, bB0,bB1,bB2,bB3, 1, 0, "4");
    KT_STEP(KT - 1, bB0,bB1,bB2,bB3, bA0,bA1,bA2,bA3, 0, 0, "0");

#undef KT_STEP
#undef LOADB8

    // 32x32 C/D layout: col=lane&31, row=(reg&3)+8*(reg>>2)+4*(lane>>5)
#pragma unroll
    for (int i = 0; i < 4; ++i) {
        int rbase = row0 + wm * 128 + i * 32 + 4 * (l >> 5);
#pragma unroll
        for (int j = 0; j < 2; ++j) {
            int col = col0 + wn * 64 + j * 32 + (l & 31);
            float bv = bias ? bias[col] : 0.f;
#pragma unroll
            for (int reg = 0; reg < 16; ++reg) {
                int row = rbase + (reg & 3) + 8 * (reg >> 2);
                float v = acc[i][j][reg] + bv;
                if (RESID) v += (float)resid[(size_t)row * N + col];
                if (RELU) v = fmaxf(v, 0.f);
                if (OMODE == 1)
                    ((unsigned char*)C)[(size_t)row * N + col] = to_fp8(v);
                else if (OMODE == 2)
                    ((bf16_t*)C)[(size_t)row * N + col] = (bf16_t)v;
                else
                    ((float*)C)[(size_t)row * N + col] = v;
            }
        }
    }
}

template<int OMODE, int RELU, int RESID>
static inline void launch_fp8_t(const unsigned char* A, const unsigned char* Bp, const float* bias,
                                void* C, const bf16_t* resid, int rows, int Kd, int N, hipStream_t st) {
    int nx = N / 256, ny = rows / 256;
    gemm_fp8<OMODE, RELU, RESID><<<dim3(nx * ny), 512, 0, st>>>(A, Bp, bias, C, resid, Kd, N, nx, ny);
}

// ---------------------------------------------------------------- transpose fp32 W[Kd][N] -> bf16 Wt[N][Kd]
__global__ __launch_bounds__(256) void transpose_bf16(
    const float* __restrict__ W, bf16_t* __restrict__ Wt, int Kd, int N)
{
    __shared__ float t[32][33];
    int bx = blockIdx.x * 32, by = blockIdx.y * 32;
    int x = threadIdx.x & 31, y = threadIdx.x >> 5;
#pragma unroll
    for (int yy = y; yy < 32; yy += 8) t[yy][x] = W[(size_t)(by + yy) * N + bx + x];
    __syncthreads();
#pragma unroll
    for (int yy = y; yy < 32; yy += 8) Wt[(size_t)(bx + yy) * Kd + by + x] = (bf16_t)t[x][yy];
}

// ---------------------------------------------------------------- pack fp32 W[Kd][N] -> fragment-packed fp8
// P[cg][kt][s][half][chunk][col][16B]; byte b of chunk = k = kt*128+s*64+half*32+chunk*16+b
__global__ __launch_bounds__(256) void pack_fp8(
    const float* __restrict__ W, unsigned char* __restrict__ P, int Kd, int N)
{
    __shared__ float t[32][33];
    int bx = blockIdx.x * 32, by = blockIdx.y * 32;     // bx: col, by: k
    int x = threadIdx.x & 31, y = threadIdx.x >> 5;
#pragma unroll
    for (int yy = y; yy < 32; yy += 8) t[yy][x] = W[(size_t)(by + yy) * N + bx + x];
    __syncthreads();
    int xg = threadIdx.x & 7, yo = threadIdx.x >> 3;
    int lo = __builtin_amdgcn_cvt_pk_fp8_f32(t[xg * 4 + 0][yo], t[xg * 4 + 1][yo], 0, false);
    int both = __builtin_amdgcn_cvt_pk_fp8_f32(t[xg * 4 + 2][yo], t[xg * 4 + 3][yo], lo, true);
    int cg = blockIdx.x;
    int kt = by >> 7;
    int s = (by >> 6) & 1;
    int half = (by >> 5) & 1;
    int chunk = xg >> 2;
    size_t off = (((size_t)cg * (Kd >> 7) + kt) * 4096) + s * 2048 + half * 1024
               + chunk * 512 + yo * 16 + (xg & 3) * 4;
    *(int*)(P + off) = both;
}

// ---------------------------------------------------------------- cand fp32 -> bf16 + fp8
__global__ __launch_bounds__(256) void cvt_cand(
    const float* __restrict__ x, bf16_t* __restrict__ yb,
    unsigned char* __restrict__ yq, int n4)
{
    int i = blockIdx.x * 256 + threadIdx.x;
    if (i < n4) {
        float4 v = ((const float4*)x)[i];
        bf16_t o4[4] = {(bf16_t)v.x, (bf16_t)v.y, (bf16_t)v.z, (bf16_t)v.w};
        ((uint2*)yb)[i] = *(uint2*)o4;
        int lo = __builtin_amdgcn_cvt_pk_fp8_f32(v.x, v.y, 0, false);
        int both = __builtin_amdgcn_cvt_pk_fp8_f32(v.z, v.w, lo, true);
        ((int*)yq)[i] = both;
    }
}

// ---------------------------------------------------------------- bias pack [bq|bk|bv] (2304)
__global__ __launch_bounds__(256) void pack_bias(
    const float* __restrict__ bq, const float* __restrict__ bk,
    const float* __restrict__ bv, float* __restrict__ o)
{
    int i = blockIdx.x * 256 + threadIdx.x;
    if (i < 768) { o[i] = bq[i]; o[i + 768] = bk[i]; o[i + 1536] = bv[i]; }
}

// ---------------------------------------------------------------- span means (fp32 + bf16 + fp8)
__global__ __launch_bounds__(256) void spans_kernel(
    const float* __restrict__ txt, const int* __restrict__ starts,
    const int* __restrict__ lens, float* __restrict__ mention,
    unsigned char* __restrict__ mentionq, bf16_t* __restrict__ mentionb,
    bf16_t* __restrict__ ctxb)
{
    int m = blockIdx.x;
    int st = starts[m], ln = lens[m];
    int en = st + ln;
    int cs = st - CTX_W; if (cs < 0) cs = 0;
    int ce = en + CTX_W; if (ce > S_LEN - 1) ce = S_LEN - 1;
    int c = threadIdx.x;
    float s0 = 0.f, s1 = 0.f, s2 = 0.f;
    for (int r = st; r <= en; ++r) {
        const float* tr = txt + (size_t)r * D_DIM;
        s0 += tr[c]; s1 += tr[c + 256]; s2 += tr[c + 512];
    }
    float inv = 1.f / (float)(ln + 1);
    float v0 = s0 * inv, v1 = s1 * inv, v2 = s2 * inv;
    float* mp = mention + (size_t)m * D_DIM;
    bf16_t* mb = mentionb + (size_t)m * D_DIM;
    unsigned char* mq = mentionq + (size_t)m * D_DIM;
    mp[c] = v0; mp[c + 256] = v1; mp[c + 512] = v2;
    mb[c] = (bf16_t)v0; mb[c + 256] = (bf16_t)v1; mb[c + 512] = (bf16_t)v2;
    mq[c] = to_fp8(v0); mq[c + 256] = to_fp8(v1); mq[c + 512] = to_fp8(v2);

    s0 = 0.f; s1 = 0.f; s2 = 0.f;
    for (int r = cs; r < ce; ++r) {
        const float* tr = txt + (size_t)r * D_DIM;
        s0 += tr[c]; s1 += tr[c + 256]; s2 += tr[c + 512];
    }
    inv = 1.f / (float)(ce - cs);
    bf16_t* cp = ctxb + (size_t)m * D_DIM;
    cp[c] = (bf16_t)(s0 * inv); cp[c + 256] = (bf16_t)(s1 * inv); cp[c + 512] = (bf16_t)(s2 * inv);
}

// ---------------------------------------------------------------- uni_w2 column-mean
__global__ __launch_bounds__(256) void w2bar_kernel(
    const float* __restrict__ uni_w2, const float* __restrict__ uni_b2,
    float* __restrict__ w2bar, float* __restrict__ b2bar)
{
    __shared__ float sbuf[4];
    int d = blockIdx.x;
    float s = 0.f;
    if (d < D_DIM) {
        for (int j = threadIdx.x; j < D_DIM; j += 256) s += uni_w2[(size_t)d * D_DIM + j];
        s = block_reduce_sum(s, sbuf);
        if (threadIdx.x == 0) w2bar[d] = s * (1.f / (float)D_DIM);
    } else {
        for (int j = threadIdx.x; j < D_DIM; j += 256) s += uni_b2[j];
        s = block_reduce_sum(s, sbuf);
        if (threadIdx.x == 0) *b2bar = s * (1.f / (float)D_DIM);
    }
}

// ---------------------------------------------------------------- 2x2 attention (QKV stride 2304, fp8 obuf out)
__global__ __launch_bounds__(512) void attn_kernel(
    const bf16_t* __restrict__ qkvm, const bf16_t* __restrict__ qkvc,
    unsigned char* __restrict__ o, int g0)
{
    int lc = blockIdx.x;
    int gg = g0 + lc;
    int m = gg >> 5;
    int h = threadIdx.x >> 6;
    int lane = threadIdx.x & 63;
    const bf16_t* bm = qkvm + (size_t)m * 2304 + h * DH_DIM;
    const bf16_t* bc = qkvc + (size_t)lc * 2304 + h * DH_DIM;

    float s00 = 0.f, s01 = 0.f, s10 = 0.f, s11 = 0.f;
    int d = lane * 2;
    if (lane < 48) {
        float qm0, qm1, km0, km1, qc0, qc1, kc0, kc1;
        ld2(bm + d, qm0, qm1);
        ld2(bm + 768 + d, km0, km1);
        ld2(bc + d, qc0, qc1);
        ld2(bc + 768 + d, kc0, kc1);
        s00 = qm0 * km0 + qm1 * km1;
        s01 = qm0 * kc0 + qm1 * kc1;
        s10 = qc0 * km0 + qc1 * km1;
        s11 = qc0 * kc0 + qc1 * kc1;
    }
#pragma unroll
    for (int off = 32; off; off >>= 1) {
        s00 += __shfl_down(s00, off); s01 += __shfl_down(s01, off);
        s10 += __shfl_down(s10, off); s11 += __shfl_down(s11, off);
    }
    s00 = __shfl(s00, 0); s01 = __shfl(s01, 0);
    s10 = __shfl(s10, 0); s11 = __shfl(s11, 0);
    const float sc = 0.1020620726159658f;  // 1/sqrt(96)
    s00 *= sc; s01 *= sc; s10 *= sc; s11 *= sc;
    float m0 = fmaxf(s00, s01), m1 = fmaxf(s10, s11);
    float e00 = expf(s00 - m0), e01 = expf(s01 - m0);
    float e10 = expf(s10 - m1), e11 = expf(s11 - m1);
    float i0 = 1.f / (e00 + e01), i1 = 1.f / (e10 + e11);
    float a00 = e00 * i0, a01 = e01 * i0, a10 = e10 * i1, a11 = e11 * i1;

    unsigned char* o0 = o + ((size_t)lc * 2) * D_DIM + h * DH_DIM;
    unsigned char* o1 = o0 + D_DIM;
    if (lane < 48) {
        float vm0, vm1, vc0, vc1;
        ld2(bm + 1536 + d, vm0, vm1);
        ld2(bc + 1536 + d, vc0, vc1);
        unsigned r0 = __builtin_amdgcn_cvt_pk_fp8_f32(a00 * vm0 + a01 * vc0, a00 * vm1 + a01 * vc1, 0, false);
        unsigned r1 = __builtin_amdgcn_cvt_pk_fp8_f32(a10 * vm0 + a11 * vc0, a10 * vm1 + a11 * vc1, 0, false);
        *(unsigned short*)(o0 + d) = (unsigned short)(r0 & 0xffff);
        *(unsigned short*)(o1 + d) = (unsigned short)(r1 & 0xffff);
    }
}

// ---------------------------------------------------------------- LN1 (wave-per-row; full candb indexed by gg)
__global__ __launch_bounds__(256) void ln1_kernel(
    const bf16_t* __restrict__ x1pre, const float* __restrict__ mention,
    const bf16_t* __restrict__ candb, const float* __restrict__ g,
    const float* __restrict__ b, bf16_t* __restrict__ x1f,
    unsigned char* __restrict__ x1q, int g0)
{
    int w = threadIdx.x >> 6, l = threadIdx.x & 63;
    int r = blockIdx.x * 4 + w;
    int lc = r >> 1, pos = r & 1;
    int gg = g0 + lc, m = gg >> 5;
    float v[12];
    const bf16_t* pr = x1pre + (size_t)r * D_DIM;
    if (pos) {
        const bf16_t* xr = candb + (size_t)gg * D_DIM;
#pragma unroll
        for (int i = 0; i < 12; ++i) { int j = l + i * 64; v[i] = (float)xr[j] + (float)pr[j]; }
    } else {
        const float* xr = mention + (size_t)m * D_DIM;
#pragma unroll
        for (int i = 0; i < 12; ++i) { int j = l + i * 64; v[i] = xr[j] + (float)pr[j]; }
    }
    float s = 0.f;
#pragma unroll
    for (int i = 0; i < 12; ++i) s += v[i];
    float mu = wave_sum(s) * (1.f / (float)D_DIM);
    float vv = 0.f;
#pragma unroll
    for (int i = 0; i < 12; ++i) { float d = v[i] - mu; vv += d * d; }
    float var = wave_sum(vv) * (1.f / (float)D_DIM);
    float inv = rsqrtf(var + 1e-5f);
    bf16_t* fp = x1f + (size_t)r * D_DIM;
    unsigned char* qp = x1q + (size_t)r * D_DIM;
#pragma unroll
    for (int i = 0; i < 12; ++i) {
        int j = l + i * 64;
        float o = (v[i] - mu) * inv * g[j] + b[j];
        fp[j] = (bf16_t)o;
        qp[j] = to_fp8(o);
    }
}

// ---------------------------------------------------------------- fused heads (wave-per-pair): LN2 + atg + relik + uni
__global__ __launch_bounds__(256) void heads_kernel(
    const bf16_t* __restrict__ y,
    const float* __restrict__ g2, const float* __restrict__ b2g,
    const float* __restrict__ Ar, const float* __restrict__ Au,
    const bf16_t* __restrict__ ru, const float* __restrict__ rw2,
    const float* __restrict__ rb2, const float* __restrict__ w2bar,
    const float* __restrict__ b2bar, float* __restrict__ out, int g0)
{
    int w = threadIdx.x >> 6, l = threadIdx.x & 63;
    int lc = blockIdx.x * 4 + w;
    int gg = g0 + lc, m = gg >> 5;
    const bf16_t* y0 = y + (size_t)(2 * lc) * D_DIM;
    const bf16_t* y1 = y0 + D_DIM;
    float v0[12], v1[12];
    float s0 = 0.f, s1 = 0.f;
#pragma unroll
    for (int i = 0; i < 12; ++i) {
        int j = l + i * 64;
        v0[i] = (float)y0[j]; v1[i] = (float)y1[j];
        s0 += v0[i]; s1 += v1[i];
    }
    float mu0 = wave_sum(s0) * (1.f / (float)D_DIM);
    float mu1 = wave_sum(s1) * (1.f / (float)D_DIM);
    float q0 = 0.f, q1 = 0.f;
#pragma unroll
    for (int i = 0; i < 12; ++i) {
        float d0 = v0[i] - mu0, d1 = v1[i] - mu1;
        q0 += d0 * d0; q1 += d1 * d1;
    }
    float inv0 = rsqrtf(wave_sum(q0) * (1.f / (float)D_DIM) + 1e-5f);
    float inv1 = rsqrtf(wave_sum(q1) * (1.f / (float)D_DIM) + 1e-5f);

    const float* ar = Ar + (size_t)m * D_DIM;
    const float* au = Au + (size_t)m * D_DIM;
    const bf16_t* br = ru + (size_t)lc * 1536;
    const bf16_t* bu = br + 768;

    float dd = 0.f, aa = 0.f, bb = 0.f, rs = 0.f, us = 0.f;
#pragma unroll
    for (int i = 0; i < 12; ++i) {
        int j = l + i * 64;
        float e0 = (v0[i] - mu0) * inv0 * g2[j] + b2g[j];
        float e1 = (v1[i] - mu1) * inv1 * g2[j] + b2g[j];
        dd += e0 * e1; aa += e0 * e0; bb += e1 * e1;
        rs += fmaxf(ar[j] + (float)br[j], 0.f) * rw2[j];
        us += fmaxf(au[j] + (float)bu[j], 0.f) * w2bar[j];
    }
    dd = wave_sum(dd); aa = wave_sum(aa); bb = wave_sum(bb);
    rs = wave_sum(rs); us = wave_sum(us);
    if (l == 0) {
        float n0 = fmaxf(sqrtf(aa), 1e-8f);
        float n1 = fmaxf(sqrtf(bb), 1e-8f);
        out[MK_CNT + gg] = dd / (n0 * n1);
        out[gg] = rs + rb2[0];
        float z = us + *b2bar;
        out[2 * MK_CNT + gg] = 1.f / (1.f + expf(-z));
    }
}

// ---------------------------------------------------------------- host
extern "C" void kernel_launch(void* const* d_in, const int* in_sizes, int n_in,
                              void* d_out, int out_size, void* d_ws, size_t ws_size,
                              hipStream_t stream) {
    const float* text     = (const float*)d_in[0];
    const float* cand     = (const float*)d_in[1];
    const int*   starts   = (const int*)d_in[2];
    const int*   lens     = (const int*)d_in[3];
    const float* relik_w1 = (const float*)d_in[4];
    const float* relik_b1 = (const float*)d_in[5];
    const float* relik_w2 = (const float*)d_in[6];
    const float* relik_b2 = (const float*)d_in[7];
    const float* wq = (const float*)d_in[8];
    const float* bq = (const float*)d_in[9];
    const float* wk = (const float*)d_in[10];
    const float* bk = (const float*)d_in[11];
    const float* wv = (const float*)d_in[12];
    const float* bv = (const float*)d_in[13];
    const float* wo = (const float*)d_in[14];
    const float* bo = (const float*)d_in[15];
    const float* ln1_g = (const float*)d_in[16];
    const float* ln1_b = (const float*)d_in[17];
    const float* ffn_w1 = (const float*)d_in[18];
    const float* ffn_b1 = (const float*)d_in[19];
    const float* ffn_w2 = (const float*)d_in[20];
    const float* ffn_b2 = (const float*)d_in[21];
    const float* ln2_g = (const float*)d_in[22];
    const float* ln2_b = (const float*)d_in[23];
    const float* uni_w1 = (const float*)d_in[24];
    const float* uni_b1 = (const float*)d_in[25];
    const float* uni_w2 = (const float*)d_in[26];
    const float* uni_b2 = (const float*)d_in[27];
    float* out = (float*)d_out;

    const size_t MD = (size_t)M_CNT * D_DIM;
    const size_t DD = (size_t)D_DIM * D_DIM;

    // fixed ~26.4M floats; per chunk 4224*NC floats (aliased regions, see below)
    size_t fixed_f = 26500000;
    int NC = 32768;
    while (NC > 256 && (fixed_f + (size_t)NC * 4224) * 4 > ws_size) NC >>= 1;
    const size_t NCD = (size_t)NC * D_DIM;

    float* p = (float*)d_ws;
    float* mention = p; p += MD;
    float* Ar      = p; p += MD;
    float* Au      = p; p += MD;
    float* bqkv    = p; p += 2304;
    float* w2bar   = p; p += 768;
    float* b2bar   = p; p += 64;
    bf16_t* mentionb = (bf16_t*)p; p += MD / 2;
    bf16_t* ctxb     = (bf16_t*)p; p += MD / 2;
    unsigned char* mentionq = (unsigned char*)p; p += MD / 4;
    bf16_t* qkvm     = (bf16_t*)p; p += (size_t)M_CNT * 2304 / 2;
    bf16_t* relikAT  = (bf16_t*)p; p += DD / 2;
    bf16_t* uniAT    = (bf16_t*)p; p += DD / 2;
    bf16_t* wruT     = (bf16_t*)p; p += 2 * DD / 2;        // [relikB | uniB] bf16 [1536][768]
    unsigned char* wqkvq = (unsigned char*)p; p += 3 * DD / 4;  // [q|k|v] packed fp8
    unsigned char* woq   = (unsigned char*)p; p += DD / 4;
    unsigned char* w1q = (unsigned char*)p; p += (size_t)3072 * 768 / 4;
    unsigned char* w2q = (unsigned char*)p; p += (size_t)3072 * 768 / 4;
    bf16_t* candb    = (bf16_t*)p; p += (size_t)MK_CNT * D_DIM / 2;
    unsigned char* candq = (unsigned char*)p; p += (size_t)MK_CNT * D_DIM / 4;

    // per-chunk, lifetime-aliased (see R2 notes)
    bf16_t* qkvcb = (bf16_t*)p;
    bf16_t* x1f   = (bf16_t*)p;
    unsigned char* x1q = (unsigned char*)(x1f + 2 * NCD);
    p += (size_t)NC * 2304 / 2;                  // 1152*NC floats
    bf16_t* rucb  = (bf16_t*)p; p += (size_t)NC * 1536 / 2;
    bf16_t* x1pre = (bf16_t*)p;
    bf16_t* x2f   = x1pre;
    p += NCD;
    unsigned char* hb   = (unsigned char*)p;
    unsigned char* obuf = hb;
    p += (size_t)NC * 1536;

    // ---- weight prep ----
    dim3 t768(768 / 32, 768 / 32);
    pack_fp8<<<t768, 256, 0, stream>>>(wq, wqkvq, 768, 768);
    pack_fp8<<<t768, 256, 0, stream>>>(wk, wqkvq + DD, 768, 768);
    pack_fp8<<<t768, 256, 0, stream>>>(wv, wqkvq + 2 * DD, 768, 768);
    pack_fp8<<<t768, 256, 0, stream>>>(wo, woq, 768, 768);
    transpose_bf16<<<t768, 256, 0, stream>>>(relik_w1 + DD, wruT, 768, 768);
    transpose_bf16<<<t768, 256, 0, stream>>>(uni_w1 + DD, wruT + DD, 768, 768);
    transpose_bf16<<<t768, 256, 0, stream>>>(relik_w1, relikAT, 768, 768);
    transpose_bf16<<<t768, 256, 0, stream>>>(uni_w1, uniAT, 768, 768);
    pack_fp8<<<dim3(3072 / 32, 768 / 32), 256, 0, stream>>>(ffn_w1, w1q, 768, 3072);
    pack_fp8<<<dim3(768 / 32, 3072 / 32), 256, 0, stream>>>(ffn_w2, w2q, 3072, 768);
    pack_bias<<<3, 256, 0, stream>>>(bq, bk, bv, bqkv);
    w2bar_kernel<<<D_DIM + 1, 256, 0, stream>>>(uni_w2, uni_b2, w2bar, b2bar);
    cvt_cand<<<(MK_CNT * D_DIM / 4 + 255) / 256, 256, 0, stream>>>(cand, candb, candq, MK_CNT * D_DIM / 4);

    // ---- per-mention precompute ----
    spans_kernel<<<M_CNT, 256, 0, stream>>>(text, starts, lens, mention, mentionq, mentionb, ctxb);
    launch_fp8_t<2, 0, 0>(mentionq, wqkvq, bqkv, qkvm, nullptr, M_CNT, 768, 2304, stream);
    launch_gemm(mentionb, relikAT, relik_b1, Ar, M_CNT, 768, 768, false, false, stream);
    launch_gemm(ctxb, uniAT, uni_b1, Au, M_CNT, 768, 768, false, false, stream);

    int nch = MK_CNT / NC;
    for (int c = 0; c < nch; ++c) {
        int g0 = c * NC;
        launch_fp8_t<2, 0, 0>(candq + (size_t)g0 * D_DIM, wqkvq, bqkv, qkvcb, nullptr, NC, 768, 2304, stream);
        launch_gemm(candb + (size_t)g0 * D_DIM, wruT, nullptr, rucb, NC, 768, 1536, false, true, stream);

        attn_kernel<<<NC, 512, 0, stream>>>(qkvm, qkvcb, obuf, g0);

        launch_fp8_t<2, 0, 0>(obuf, woq, bo, x1pre, nullptr, 2 * NC, 768, 768, stream);
        ln1_kernel<<<2 * NC / 4, 256, 0, stream>>>(x1pre, mention, candb,
                                                   ln1_g, ln1_b, x1f, x1q, g0);

        launch_fp8_t<1, 1, 0>(x1q, w1q, ffn_b1, hb, nullptr, 2 * NC, 768, 3072, stream);
        // FFN2 with fused +x1 residual -> x2f holds LN2 input
        launch_fp8_t<2, 0, 1>(hb, w2q, ffn_b2, x2f, x1f, 2 * NC, 3072, 768, stream);

        heads_kernel<<<NC / 4, 256, 0, stream>>>(x2f, ln2_g, ln2_b, Ar, Au, rucb,
                                                 relik_w2, relik_b2, w2bar, b2bar, out, g0);
    }
}

// Round 8
// 1169.472 us; speedup vs baseline: 3.0585x; 3.0585x over previous
//
#include <hip/hip_runtime.h>
#include <math.h>

#define S_LEN 4096
#define D_DIM 768
#define M_CNT 1024
#define K_CNT 32
#define MK_CNT 32768
#define DH_DIM 96
#define CTX_W 10

typedef __bf16 bf16_t;
typedef bf16_t bf16x8 __attribute__((ext_vector_type(8)));
typedef float f32x4 __attribute__((ext_vector_type(4)));
typedef float f32x16 __attribute__((ext_vector_type(16)));
typedef int i32x4 __attribute__((ext_vector_type(4)));
typedef int i32x8 __attribute__((ext_vector_type(8)));

// ---------------------------------------------------------------- reduces
__device__ __forceinline__ float block_reduce_sum(float v, float* sbuf) {
#pragma unroll
    for (int off = 32; off; off >>= 1) v += __shfl_down(v, off);
    __syncthreads();
    int wave = threadIdx.x >> 6;
    int lane = threadIdx.x & 63;
    if (lane == 0) sbuf[wave] = v;
    __syncthreads();
    return sbuf[0] + sbuf[1] + sbuf[2] + sbuf[3];
}

__device__ __forceinline__ float wave_sum(float v) {
#pragma unroll
    for (int off = 32; off; off >>= 1) v += __shfl_down(v, off);
    return __shfl(v, 0);
}

__device__ __forceinline__ unsigned char to_fp8(float v) {
    return (unsigned char)(__builtin_amdgcn_cvt_pk_fp8_f32(v, v, 0, false) & 0xff);
}

__device__ __forceinline__ void ld2(const bf16_t* p, float& a, float& b) {
    ushort2 u = *(const ushort2*)p;
    a = __uint_as_float((unsigned)u.x << 16);
    b = __uint_as_float((unsigned)u.y << 16);
}

__device__ __forceinline__ float bfu(unsigned short u) {
    return __uint_as_float((unsigned)u << 16);
}

// ---------------------------------------------------------------- bf16 MFMA GEMM (128x128 tile)
template<int OUT_BF16, int RELU>
__global__ __launch_bounds__(256, 2) void gemm_mfma(
    const bf16_t* __restrict__ A, const bf16_t* __restrict__ Bt,
    const float* __restrict__ bias, void* __restrict__ C,
    int Kd, int N, int nx, int ny)
{
    __shared__ bf16_t As[128 * 64];
    __shared__ bf16_t Bs[128 * 64];
    const int tid = threadIdx.x;
    const int w = tid >> 6, l = tid & 63;
    int per = 8 * nx;
    int g = blockIdx.x / per, rr = blockIdx.x % per;
    int gs = ny - g * 8; if (gs > 8) gs = 8;
    const int row0 = (g * 8 + rr % gs) * 128, col0 = (rr / gs) * 128;

    const int srow = w * 8 + (l >> 3);
    const int gchunk = (l & 7) ^ ((l >> 3) & 7);
    const bf16_t* gA = A + (size_t)(row0 + srow) * Kd + gchunk * 8;
    const bf16_t* gB = Bt + (size_t)(col0 + srow) * Kd + gchunk * 8;

    const int wm = w >> 1, wn = w & 1;
    f32x4 acc[4][4] = {};

    for (int k0 = 0; k0 < Kd; k0 += 64) {
#pragma unroll
        for (int c = 0; c < 4; ++c) {
            __builtin_amdgcn_global_load_lds(
                (const __attribute__((address_space(1))) void*)(gA + (size_t)(c * 32) * Kd + k0),
                (__attribute__((address_space(3))) void*)(As + (c * 256 + w * 64) * 8), 16, 0, 0);
            __builtin_amdgcn_global_load_lds(
                (const __attribute__((address_space(1))) void*)(gB + (size_t)(c * 32) * Kd + k0),
                (__attribute__((address_space(3))) void*)(Bs + (c * 256 + w * 64) * 8), 16, 0, 0);
        }
        __syncthreads();
#pragma unroll
        for (int ks = 0; ks < 2; ++ks) {
            bf16x8 af[4], bfr[4];
#pragma unroll
            for (int i = 0; i < 4; ++i) {
                int arow = wm * 64 + i * 16 + (l & 15);
                int slot = (ks * 4 + (l >> 4)) ^ (l & 7);
                af[i] = *(const bf16x8*)(As + arow * 64 + slot * 8);
                int brow = wn * 64 + i * 16 + (l & 15);
                bfr[i] = *(const bf16x8*)(Bs + brow * 64 + slot * 8);
            }
#pragma unroll
            for (int i = 0; i < 4; ++i)
#pragma unroll
                for (int j = 0; j < 4; ++j)
                    acc[i][j] = __builtin_amdgcn_mfma_f32_16x16x32_bf16(af[i], bfr[j], acc[i][j], 0, 0, 0);
        }
        __syncthreads();
    }

#pragma unroll
    for (int i = 0; i < 4; ++i) {
        int row = row0 + wm * 64 + i * 16 + (l >> 4) * 4;
#pragma unroll
        for (int j = 0; j < 4; ++j) {
            int col = col0 + wn * 64 + j * 16 + (l & 15);
            float bv = bias ? bias[col] : 0.f;
#pragma unroll
            for (int r = 0; r < 4; ++r) {
                float v = acc[i][j][r] + bv;
                if (RELU) v = fmaxf(v, 0.f);
                if (OUT_BF16) ((bf16_t*)C)[(size_t)(row + r) * N + col] = (bf16_t)v;
                else          ((float*)C)[(size_t)(row + r) * N + col] = v;
            }
        }
    }
}

static inline void launch_gemm(const bf16_t* A, const bf16_t* Bt, const float* bias, void* C,
                               int rows, int Kd, int N, bool relu, bool outbf, hipStream_t st) {
    int nx = N / 128, ny = rows / 128;
    dim3 grid(nx * ny);
    if (outbf) {
        if (relu) gemm_mfma<1, 1><<<grid, 256, 0, st>>>(A, Bt, bias, C, Kd, N, nx, ny);
        else      gemm_mfma<1, 0><<<grid, 256, 0, st>>>(A, Bt, bias, C, Kd, N, nx, ny);
    } else {
        if (relu) gemm_mfma<0, 1><<<grid, 256, 0, st>>>(A, Bt, bias, C, Kd, N, nx, ny);
        else      gemm_mfma<0, 0><<<grid, 256, 0, st>>>(A, Bt, bias, C, Kd, N, nx, ny);
    }
}

// ---------------------------------------------------------------- fp8 MX-MFMA GEMM
// R6 verified structure (best measured: 112us, MfmaUtil 27.7%, no spill).
// 256x128 tile, 4 waves 2x2, per-wave 128x64, BK=128, serial stage->sync->
// compute, 2 blocks/CU. B operand bypasses LDS (fragment-packed global->VGPR).
// OMODE: 0=f32, 1=fp8, 2=bf16. RESID: add bf16 residual at [row][col] before store.
template<int OMODE, int RELU, int RESID>
__global__ __launch_bounds__(256, 2) void gemm_fp8(
    const unsigned char* __restrict__ A, const unsigned char* __restrict__ Bp,
    const float* __restrict__ bias, void* __restrict__ C,
    const bf16_t* __restrict__ resid,
    int Kd, int N, int nx, int ny)
{
    __shared__ unsigned char As[256 * 128];
    const int tid = threadIdx.x;
    const int w = tid >> 6, l = tid & 63;
    int per = 8 * nx;
    int g = blockIdx.x / per, rrb = blockIdx.x % per;
    int gs = ny - g * 8; if (gs > 8) gs = 8;
    const int row0 = (g * 8 + rrb % gs) * 256, col0 = (rrb / gs) * 128;
    const int wm = w >> 1, wn = w & 1;
    const int SA = 0x7F7F7F7F;          // E8M0 scale = 1.0 in every byte
    const int KT = Kd >> 7;

    const int srow = w * 8 + (l >> 3);
    const int gch = (l & 7) ^ ((l >> 3) & 7);
    const unsigned char* gA = A + (size_t)(row0 + srow) * Kd + gch * 16;

    const int cg0 = (col0 >> 5) + wn * 2;
    const unsigned char* gB0 = Bp + (size_t)cg0 * KT * 4096 + (l >> 5) * 1024 + (l & 31) * 16;
    const unsigned char* gB1 = gB0 + (size_t)KT * 4096;

    f32x16 acc[4][2] = {};

    for (int kt = 0; kt < KT; ++kt) {
#pragma unroll
        for (int q = 0; q < 8; ++q)
            __builtin_amdgcn_global_load_lds(
                (const __attribute__((address_space(1))) void*)(gA + (size_t)(q * 32) * Kd + kt * 128),
                (__attribute__((address_space(3))) void*)(As + (q * 256 + w * 64) * 16), 16, 0, 0);

        const unsigned char* p0 = gB0 + (size_t)kt * 4096;
        const unsigned char* p1 = gB1 + (size_t)kt * 4096;
        i32x4 b00l = *(const i32x4*)(p0);
        i32x4 b00h = *(const i32x4*)(p0 + 512);
        i32x4 b01l = *(const i32x4*)(p0 + 2048);
        i32x4 b01h = *(const i32x4*)(p0 + 2560);
        i32x4 b10l = *(const i32x4*)(p1);
        i32x4 b10h = *(const i32x4*)(p1 + 512);
        i32x4 b11l = *(const i32x4*)(p1 + 2048);
        i32x4 b11h = *(const i32x4*)(p1 + 2560);

        __syncthreads();   // drains A->LDS AND B->VGPR (vmcnt 0)

#pragma unroll
        for (int s = 0; s < 2; ++s) {
            int cb = s * 4 + ((l >> 5) << 1);
            i32x8 af[4], bfr[2];
#pragma unroll
            for (int i = 0; i < 4; ++i) {
                int row = wm * 128 + i * 32 + (l & 31);
                int sl0 = cb ^ (row & 7);
                int sl1 = (cb + 1) ^ (row & 7);
                i32x4 lo = *(const i32x4*)(As + (row * 8 + sl0) * 16);
                i32x4 hi = *(const i32x4*)(As + (row * 8 + sl1) * 16);
                i32x8 a;
                a[0] = lo[0]; a[1] = lo[1]; a[2] = lo[2]; a[3] = lo[3];
                a[4] = hi[0]; a[5] = hi[1]; a[6] = hi[2]; a[7] = hi[3];
                af[i] = a;
            }
            {
                i32x4 lo = s ? b01l : b00l;
                i32x4 hi = s ? b01h : b00h;
                i32x8 b;
                b[0] = lo[0]; b[1] = lo[1]; b[2] = lo[2]; b[3] = lo[3];
                b[4] = hi[0]; b[5] = hi[1]; b[6] = hi[2]; b[7] = hi[3];
                bfr[0] = b;
                lo = s ? b11l : b10l;
                hi = s ? b11h : b10h;
                b[0] = lo[0]; b[1] = lo[1]; b[2] = lo[2]; b[3] = lo[3];
                b[4] = hi[0]; b[5] = hi[1]; b[6] = hi[2]; b[7] = hi[3];
                bfr[1] = b;
            }
#pragma unroll
            for (int i = 0; i < 4; ++i)
#pragma unroll
                for (int j = 0; j < 2; ++j)
                    acc[i][j] = __builtin_amdgcn_mfma_scale_f32_32x32x64_f8f6f4(
                        af[i], bfr[j], acc[i][j], 0, 0, 0, SA, 0, SA);
        }
        __syncthreads();   // As reused next kt
    }

    // 32x32 C/D layout: col=lane&31, row=(reg&3)+8*(reg>>2)+4*(lane>>5)
#pragma unroll
    for (int i = 0; i < 4; ++i) {
        int rbase = row0 + wm * 128 + i * 32 + 4 * (l >> 5);
#pragma unroll
        for (int j = 0; j < 2; ++j) {
            int col = col0 + wn * 64 + j * 32 + (l & 31);
            float bv = bias ? bias[col] : 0.f;
#pragma unroll
            for (int reg = 0; reg < 16; ++reg) {
                int row = rbase + (reg & 3) + 8 * (reg >> 2);
                float v = acc[i][j][reg] + bv;
                if (RESID) v += (float)resid[(size_t)row * N + col];
                if (RELU) v = fmaxf(v, 0.f);
                if (OMODE == 1)
                    ((unsigned char*)C)[(size_t)row * N + col] = to_fp8(v);
                else if (OMODE == 2)
                    ((bf16_t*)C)[(size_t)row * N + col] = (bf16_t)v;
                else
                    ((float*)C)[(size_t)row * N + col] = v;
            }
        }
    }
}

template<int OMODE, int RELU, int RESID>
static inline void launch_fp8_t(const unsigned char* A, const unsigned char* Bp, const float* bias,
                                void* C, const bf16_t* resid, int rows, int Kd, int N, hipStream_t st) {
    int nx = N / 128, ny = rows / 256;
    gemm_fp8<OMODE, RELU, RESID><<<dim3(nx * ny), 256, 0, st>>>(A, Bp, bias, C, resid, Kd, N, nx, ny);
}

// ---------------------------------------------------------------- transpose fp32 W[Kd][N] -> bf16 Wt[N][Kd]
__global__ __launch_bounds__(256) void transpose_bf16(
    const float* __restrict__ W, bf16_t* __restrict__ Wt, int Kd, int N)
{
    __shared__ float t[32][33];
    int bx = blockIdx.x * 32, by = blockIdx.y * 32;
    int x = threadIdx.x & 31, y = threadIdx.x >> 5;
#pragma unroll
    for (int yy = y; yy < 32; yy += 8) t[yy][x] = W[(size_t)(by + yy) * N + bx + x];
    __syncthreads();
#pragma unroll
    for (int yy = y; yy < 32; yy += 8) Wt[(size_t)(bx + yy) * Kd + by + x] = (bf16_t)t[x][yy];
}

// ---------------------------------------------------------------- pack fp32 W[Kd][N] -> fragment-packed fp8
// P[cg][kt][s][half][chunk][col][16B]; byte b of chunk = k = kt*128+s*64+half*32+chunk*16+b
__global__ __launch_bounds__(256) void pack_fp8(
    const float* __restrict__ W, unsigned char* __restrict__ P, int Kd, int N)
{
    __shared__ float t[32][33];
    int bx = blockIdx.x * 32, by = blockIdx.y * 32;     // bx: col, by: k
    int x = threadIdx.x & 31, y = threadIdx.x >> 5;
#pragma unroll
    for (int yy = y; yy < 32; yy += 8) t[yy][x] = W[(size_t)(by + yy) * N + bx + x];
    __syncthreads();
    int xg = threadIdx.x & 7, yo = threadIdx.x >> 3;
    int lo = __builtin_amdgcn_cvt_pk_fp8_f32(t[xg * 4 + 0][yo], t[xg * 4 + 1][yo], 0, false);
    int both = __builtin_amdgcn_cvt_pk_fp8_f32(t[xg * 4 + 2][yo], t[xg * 4 + 3][yo], lo, true);
    int cg = blockIdx.x;
    int kt = by >> 7;
    int s = (by >> 6) & 1;
    int half = (by >> 5) & 1;
    int chunk = xg >> 2;
    size_t off = (((size_t)cg * (Kd >> 7) + kt) * 4096) + s * 2048 + half * 1024
               + chunk * 512 + yo * 16 + (xg & 3) * 4;
    *(int*)(P + off) = both;
}

// ---------------------------------------------------------------- cand fp32 -> bf16 + fp8
__global__ __launch_bounds__(256) void cvt_cand(
    const float* __restrict__ x, bf16_t* __restrict__ yb,
    unsigned char* __restrict__ yq, int n4)
{
    int i = blockIdx.x * 256 + threadIdx.x;
    if (i < n4) {
        float4 v = ((const float4*)x)[i];
        bf16_t o4[4] = {(bf16_t)v.x, (bf16_t)v.y, (bf16_t)v.z, (bf16_t)v.w};
        ((uint2*)yb)[i] = *(uint2*)o4;
        int lo = __builtin_amdgcn_cvt_pk_fp8_f32(v.x, v.y, 0, false);
        int both = __builtin_amdgcn_cvt_pk_fp8_f32(v.z, v.w, lo, true);
        ((int*)yq)[i] = both;
    }
}

// ---------------------------------------------------------------- bias pack [bq|bk|bv] (2304)
__global__ __launch_bounds__(256) void pack_bias(
    const float* __restrict__ bq, const float* __restrict__ bk,
    const float* __restrict__ bv, float* __restrict__ o)
{
    int i = blockIdx.x * 256 + threadIdx.x;
    if (i < 768) { o[i] = bq[i]; o[i + 768] = bk[i]; o[i + 1536] = bv[i]; }
}

// ---------------------------------------------------------------- span means (fp32 + bf16 + fp8)
__global__ __launch_bounds__(256) void spans_kernel(
    const float* __restrict__ txt, const int* __restrict__ starts,
    const int* __restrict__ lens, float* __restrict__ mention,
    unsigned char* __restrict__ mentionq, bf16_t* __restrict__ mentionb,
    bf16_t* __restrict__ ctxb)
{
    int m = blockIdx.x;
    int st = starts[m], ln = lens[m];
    int en = st + ln;
    int cs = st - CTX_W; if (cs < 0) cs = 0;
    int ce = en + CTX_W; if (ce > S_LEN - 1) ce = S_LEN - 1;
    int c = threadIdx.x;
    float s0 = 0.f, s1 = 0.f, s2 = 0.f;
    for (int r = st; r <= en; ++r) {
        const float* tr = txt + (size_t)r * D_DIM;
        s0 += tr[c]; s1 += tr[c + 256]; s2 += tr[c + 512];
    }
    float inv = 1.f / (float)(ln + 1);
    float v0 = s0 * inv, v1 = s1 * inv, v2 = s2 * inv;
    float* mp = mention + (size_t)m * D_DIM;
    bf16_t* mb = mentionb + (size_t)m * D_DIM;
    unsigned char* mq = mentionq + (size_t)m * D_DIM;
    mp[c] = v0; mp[c + 256] = v1; mp[c + 512] = v2;
    mb[c] = (bf16_t)v0; mb[c + 256] = (bf16_t)v1; mb[c + 512] = (bf16_t)v2;
    mq[c] = to_fp8(v0); mq[c + 256] = to_fp8(v1); mq[c + 512] = to_fp8(v2);

    s0 = 0.f; s1 = 0.f; s2 = 0.f;
    for (int r = cs; r < ce; ++r) {
        const float* tr = txt + (size_t)r * D_DIM;
        s0 += tr[c]; s1 += tr[c + 256]; s2 += tr[c + 512];
    }
    inv = 1.f / (float)(ce - cs);
    bf16_t* cp = ctxb + (size_t)m * D_DIM;
    cp[c] = (bf16_t)(s0 * inv); cp[c + 256] = (bf16_t)(s1 * inv); cp[c + 512] = (bf16_t)(s2 * inv);
}

// ---------------------------------------------------------------- uni_w2 column-mean
__global__ __launch_bounds__(256) void w2bar_kernel(
    const float* __restrict__ uni_w2, const float* __restrict__ uni_b2,
    float* __restrict__ w2bar, float* __restrict__ b2bar)
{
    __shared__ float sbuf[4];
    int d = blockIdx.x;
    float s = 0.f;
    if (d < D_DIM) {
        for (int j = threadIdx.x; j < D_DIM; j += 256) s += uni_w2[(size_t)d * D_DIM + j];
        s = block_reduce_sum(s, sbuf);
        if (threadIdx.x == 0) w2bar[d] = s * (1.f / (float)D_DIM);
    } else {
        for (int j = threadIdx.x; j < D_DIM; j += 256) s += uni_b2[j];
        s = block_reduce_sum(s, sbuf);
        if (threadIdx.x == 0) *b2bar = s * (1.f / (float)D_DIM);
    }
}

// ---------------------------------------------------------------- 2x2 attention (QKV stride 2304, fp8 obuf out)
__global__ __launch_bounds__(512) void attn_kernel(
    const bf16_t* __restrict__ qkvm, const bf16_t* __restrict__ qkvc,
    unsigned char* __restrict__ o, int g0)
{
    int lc = blockIdx.x;
    int gg = g0 + lc;
    int m = gg >> 5;
    int h = threadIdx.x >> 6;
    int lane = threadIdx.x & 63;
    const bf16_t* bm = qkvm + (size_t)m * 2304 + h * DH_DIM;
    const bf16_t* bc = qkvc + (size_t)lc * 2304 + h * DH_DIM;

    float s00 = 0.f, s01 = 0.f, s10 = 0.f, s11 = 0.f;
    int d = lane * 2;
    if (lane < 48) {
        float qm0, qm1, km0, km1, qc0, qc1, kc0, kc1;
        ld2(bm + d, qm0, qm1);
        ld2(bm + 768 + d, km0, km1);
        ld2(bc + d, qc0, qc1);
        ld2(bc + 768 + d, kc0, kc1);
        s00 = qm0 * km0 + qm1 * km1;
        s01 = qm0 * kc0 + qm1 * kc1;
        s10 = qc0 * km0 + qc1 * km1;
        s11 = qc0 * kc0 + qc1 * kc1;
    }
#pragma unroll
    for (int off = 32; off; off >>= 1) {
        s00 += __shfl_down(s00, off); s01 += __shfl_down(s01, off);
        s10 += __shfl_down(s10, off); s11 += __shfl_down(s11, off);
    }
    s00 = __shfl(s00, 0); s01 = __shfl(s01, 0);
    s10 = __shfl(s10, 0); s11 = __shfl(s11, 0);
    const float sc = 0.1020620726159658f;  // 1/sqrt(96)
    s00 *= sc; s01 *= sc; s10 *= sc; s11 *= sc;
    float m0 = fmaxf(s00, s01), m1 = fmaxf(s10, s11);
    float e00 = expf(s00 - m0), e01 = expf(s01 - m0);
    float e10 = expf(s10 - m1), e11 = expf(s11 - m1);
    float i0 = 1.f / (e00 + e01), i1 = 1.f / (e10 + e11);
    float a00 = e00 * i0, a01 = e01 * i0, a10 = e10 * i1, a11 = e11 * i1;

    unsigned char* o0 = o + ((size_t)lc * 2) * D_DIM + h * DH_DIM;
    unsigned char* o1 = o0 + D_DIM;
    if (lane < 48) {
        float vm0, vm1, vc0, vc1;
        ld2(bm + 1536 + d, vm0, vm1);
        ld2(bc + 1536 + d, vc0, vc1);
        unsigned r0 = __builtin_amdgcn_cvt_pk_fp8_f32(a00 * vm0 + a01 * vc0, a00 * vm1 + a01 * vc1, 0, false);
        unsigned r1 = __builtin_amdgcn_cvt_pk_fp8_f32(a10 * vm0 + a11 * vc0, a10 * vm1 + a11 * vc1, 0, false);
        *(unsigned short*)(o0 + d) = (unsigned short)(r0 & 0xffff);
        *(unsigned short*)(o1 + d) = (unsigned short)(r1 & 0xffff);
    }
}

// ---------------------------------------------------------------- LN1 (wave-per-row, VECTORIZED: lane owns j = i*256 + l*4 + k)
__global__ __launch_bounds__(256) void ln1_kernel(
    const bf16_t* __restrict__ x1pre, const float* __restrict__ mention,
    const bf16_t* __restrict__ candb, const float* __restrict__ g,
    const float* __restrict__ b, bf16_t* __restrict__ x1f,
    unsigned char* __restrict__ x1q, int g0)
{
    int w = threadIdx.x >> 6, l = threadIdx.x & 63;
    int r = blockIdx.x * 4 + w;
    int lc = r >> 1, pos = r & 1;
    int gg = g0 + lc, m = gg >> 5;
    float v[12];
    const bf16_t* pr = x1pre + (size_t)r * D_DIM;
    if (pos) {
        const bf16_t* xr = candb + (size_t)gg * D_DIM;
#pragma unroll
        for (int i = 0; i < 3; ++i) {
            int j0 = i * 256 + l * 4;
            ushort4 a = *(const ushort4*)(pr + j0);
            ushort4 c4 = *(const ushort4*)(xr + j0);
            v[i * 4 + 0] = bfu(c4.x) + bfu(a.x);
            v[i * 4 + 1] = bfu(c4.y) + bfu(a.y);
            v[i * 4 + 2] = bfu(c4.z) + bfu(a.z);
            v[i * 4 + 3] = bfu(c4.w) + bfu(a.w);
        }
    } else {
        const float* xr = mention + (size_t)m * D_DIM;
#pragma unroll
        for (int i = 0; i < 3; ++i) {
            int j0 = i * 256 + l * 4;
            ushort4 a = *(const ushort4*)(pr + j0);
            float4 mv = *(const float4*)(xr + j0);
            v[i * 4 + 0] = mv.x + bfu(a.x);
            v[i * 4 + 1] = mv.y + bfu(a.y);
            v[i * 4 + 2] = mv.z + bfu(a.z);
            v[i * 4 + 3] = mv.w + bfu(a.w);
        }
    }
    float s = 0.f;
#pragma unroll
    for (int i = 0; i < 12; ++i) s += v[i];
    float mu = wave_sum(s) * (1.f / (float)D_DIM);
    float vv = 0.f;
#pragma unroll
    for (int i = 0; i < 12; ++i) { float d = v[i] - mu; vv += d * d; }
    float var = wave_sum(vv) * (1.f / (float)D_DIM);
    float inv = rsqrtf(var + 1e-5f);
    bf16_t* fp = x1f + (size_t)r * D_DIM;
    unsigned char* qp = x1q + (size_t)r * D_DIM;
#pragma unroll
    for (int i = 0; i < 3; ++i) {
        int j0 = i * 256 + l * 4;
        float4 gv = *(const float4*)(g + j0);
        float4 bv = *(const float4*)(b + j0);
        float o0 = (v[i * 4 + 0] - mu) * inv * gv.x + bv.x;
        float o1 = (v[i * 4 + 1] - mu) * inv * gv.y + bv.y;
        float o2 = (v[i * 4 + 2] - mu) * inv * gv.z + bv.z;
        float o3 = (v[i * 4 + 3] - mu) * inv * gv.w + bv.w;
        bf16_t ob[4] = {(bf16_t)o0, (bf16_t)o1, (bf16_t)o2, (bf16_t)o3};
        *(ushort4*)(fp + j0) = *(ushort4*)ob;
        int lo = __builtin_amdgcn_cvt_pk_fp8_f32(o0, o1, 0, false);
        int both = __builtin_amdgcn_cvt_pk_fp8_f32(o2, o3, lo, true);
        *(int*)(qp + j0) = both;
    }
}

// ---------------------------------------------------------------- fused heads (wave-per-pair, VECTORIZED): LN2 + atg + relik + uni
__global__ __launch_bounds__(256) void heads_kernel(
    const bf16_t* __restrict__ y,
    const float* __restrict__ g2, const float* __restrict__ b2g,
    const float* __restrict__ Ar, const float* __restrict__ Au,
    const bf16_t* __restrict__ ru, const float* __restrict__ rw2,
    const float* __restrict__ rb2, const float* __restrict__ w2bar,
    const float* __restrict__ b2bar, float* __restrict__ out, int g0)
{
    int w = threadIdx.x >> 6, l = threadIdx.x & 63;
    int lc = blockIdx.x * 4 + w;
    int gg = g0 + lc, m = gg >> 5;
    const bf16_t* y0 = y + (size_t)(2 * lc) * D_DIM;
    const bf16_t* y1 = y0 + D_DIM;
    float v0[12], v1[12];
    float s0 = 0.f, s1 = 0.f;
#pragma unroll
    for (int i = 0; i < 3; ++i) {
        int j0 = i * 256 + l * 4;
        ushort4 a = *(const ushort4*)(y0 + j0);
        ushort4 c = *(const ushort4*)(y1 + j0);
        v0[i * 4 + 0] = bfu(a.x); v0[i * 4 + 1] = bfu(a.y);
        v0[i * 4 + 2] = bfu(a.z); v0[i * 4 + 3] = bfu(a.w);
        v1[i * 4 + 0] = bfu(c.x); v1[i * 4 + 1] = bfu(c.y);
        v1[i * 4 + 2] = bfu(c.z); v1[i * 4 + 3] = bfu(c.w);
#pragma unroll
        for (int k = 0; k < 4; ++k) { s0 += v0[i * 4 + k]; s1 += v1[i * 4 + k]; }
    }
    float mu0 = wave_sum(s0) * (1.f / (float)D_DIM);
    float mu1 = wave_sum(s1) * (1.f / (float)D_DIM);
    float q0 = 0.f, q1 = 0.f;
#pragma unroll
    for (int i = 0; i < 12; ++i) {
        float d0 = v0[i] - mu0, d1 = v1[i] - mu1;
        q0 += d0 * d0; q1 += d1 * d1;
    }
    float inv0 = rsqrtf(wave_sum(q0) * (1.f / (float)D_DIM) + 1e-5f);
    float inv1 = rsqrtf(wave_sum(q1) * (1.f / (float)D_DIM) + 1e-5f);

    const float* ar = Ar + (size_t)m * D_DIM;
    const float* au = Au + (size_t)m * D_DIM;
    const bf16_t* br = ru + (size_t)lc * 1536;
    const bf16_t* bu = br + 768;

    float dd = 0.f, aa = 0.f, bb = 0.f, rs = 0.f, us = 0.f;
#pragma unroll
    for (int i = 0; i < 3; ++i) {
        int j0 = i * 256 + l * 4;
        float4 g4 = *(const float4*)(g2 + j0);
        float4 b4 = *(const float4*)(b2g + j0);
        float4 a4 = *(const float4*)(ar + j0);
        float4 u4 = *(const float4*)(au + j0);
        ushort4 brv = *(const ushort4*)(br + j0);
        ushort4 buv = *(const ushort4*)(bu + j0);
        float4 r4 = *(const float4*)(rw2 + j0);
        float4 w4 = *(const float4*)(w2bar + j0);
        float gk[4] = {g4.x, g4.y, g4.z, g4.w};
        float bk[4] = {b4.x, b4.y, b4.z, b4.w};
        float ak[4] = {a4.x, a4.y, a4.z, a4.w};
        float uk[4] = {u4.x, u4.y, u4.z, u4.w};
        float brk[4] = {bfu(brv.x), bfu(brv.y), bfu(brv.z), bfu(brv.w)};
        float buk[4] = {bfu(buv.x), bfu(buv.y), bfu(buv.z), bfu(buv.w)};
        float rk[4] = {r4.x, r4.y, r4.z, r4.w};
        float wk4[4] = {w4.x, w4.y, w4.z, w4.w};
#pragma unroll
        for (int k = 0; k < 4; ++k) {
            float e0 = (v0[i * 4 + k] - mu0) * inv0 * gk[k] + bk[k];
            float e1 = (v1[i * 4 + k] - mu1) * inv1 * gk[k] + bk[k];
            dd += e0 * e1; aa += e0 * e0; bb += e1 * e1;
            rs += fmaxf(ak[k] + brk[k], 0.f) * rk[k];
            us += fmaxf(uk[k] + buk[k], 0.f) * wk4[k];
        }
    }
    dd = wave_sum(dd); aa = wave_sum(aa); bb = wave_sum(bb);
    rs = wave_sum(rs); us = wave_sum(us);
    if (l == 0) {
        float n0 = fmaxf(sqrtf(aa), 1e-8f);
        float n1 = fmaxf(sqrtf(bb), 1e-8f);
        out[MK_CNT + gg] = dd / (n0 * n1);
        out[gg] = rs + rb2[0];
        float z = us + *b2bar;
        out[2 * MK_CNT + gg] = 1.f / (1.f + expf(-z));
    }
}

// ---------------------------------------------------------------- host
extern "C" void kernel_launch(void* const* d_in, const int* in_sizes, int n_in,
                              void* d_out, int out_size, void* d_ws, size_t ws_size,
                              hipStream_t stream) {
    const float* text     = (const float*)d_in[0];
    const float* cand     = (const float*)d_in[1];
    const int*   starts   = (const int*)d_in[2];
    const int*   lens     = (const int*)d_in[3];
    const float* relik_w1 = (const float*)d_in[4];
    const float* relik_b1 = (const float*)d_in[5];
    const float* relik_w2 = (const float*)d_in[6];
    const float* relik_b2 = (const float*)d_in[7];
    const float* wq = (const float*)d_in[8];
    const float* bq = (const float*)d_in[9];
    const float* wk = (const float*)d_in[10];
    const float* bk = (const float*)d_in[11];
    const float* wv = (const float*)d_in[12];
    const float* bv = (const float*)d_in[13];
    const float* wo = (const float*)d_in[14];
    const float* bo = (const float*)d_in[15];
    const float* ln1_g = (const float*)d_in[16];
    const float* ln1_b = (const float*)d_in[17];
    const float* ffn_w1 = (const float*)d_in[18];
    const float* ffn_b1 = (const float*)d_in[19];
    const float* ffn_w2 = (const float*)d_in[20];
    const float* ffn_b2 = (const float*)d_in[21];
    const float* ln2_g = (const float*)d_in[22];
    const float* ln2_b = (const float*)d_in[23];
    const float* uni_w1 = (const float*)d_in[24];
    const float* uni_b1 = (const float*)d_in[25];
    const float* uni_w2 = (const float*)d_in[26];
    const float* uni_b2 = (const float*)d_in[27];
    float* out = (float*)d_out;

    const size_t MD = (size_t)M_CNT * D_DIM;
    const size_t DD = (size_t)D_DIM * D_DIM;

    // fixed ~26.4M floats; per chunk 4224*NC floats (aliased regions, see below)
    size_t fixed_f = 26500000;
    int NC = 32768;
    while (NC > 256 && (fixed_f + (size_t)NC * 4224) * 4 > ws_size) NC >>= 1;
    const size_t NCD = (size_t)NC * D_DIM;

    float* p = (float*)d_ws;
    float* mention = p; p += MD;
    float* Ar      = p; p += MD;
    float* Au      = p; p += MD;
    float* bqkv    = p; p += 2304;
    float* w2bar   = p; p += 768;
    float* b2bar   = p; p += 64;
    bf16_t* mentionb = (bf16_t*)p; p += MD / 2;
    bf16_t* ctxb     = (bf16_t*)p; p += MD / 2;
    unsigned char* mentionq = (unsigned char*)p; p += MD / 4;
    bf16_t* qkvm     = (bf16_t*)p; p += (size_t)M_CNT * 2304 / 2;
    bf16_t* relikAT  = (bf16_t*)p; p += DD / 2;
    bf16_t* uniAT    = (bf16_t*)p; p += DD / 2;
    bf16_t* wruT     = (bf16_t*)p; p += 2 * DD / 2;        // [relikB | uniB] bf16 [1536][768]
    unsigned char* wqkvq = (unsigned char*)p; p += 3 * DD / 4;  // [q|k|v] packed fp8
    unsigned char* woq   = (unsigned char*)p; p += DD / 4;
    unsigned char* w1q = (unsigned char*)p; p += (size_t)3072 * 768 / 4;
    unsigned char* w2q = (unsigned char*)p; p += (size_t)3072 * 768 / 4;
    bf16_t* candb    = (bf16_t*)p; p += (size_t)MK_CNT * D_DIM / 2;
    unsigned char* candq = (unsigned char*)p; p += (size_t)MK_CNT * D_DIM / 4;

    // per-chunk, lifetime-aliased (see R2 notes)
    bf16_t* qkvcb = (bf16_t*)p;
    bf16_t* x1f   = (bf16_t*)p;
    unsigned char* x1q = (unsigned char*)(x1f + 2 * NCD);
    p += (size_t)NC * 2304 / 2;                  // 1152*NC floats
    bf16_t* rucb  = (bf16_t*)p; p += (size_t)NC * 1536 / 2;
    bf16_t* x1pre = (bf16_t*)p;
    bf16_t* x2f   = x1pre;
    p += NCD;
    unsigned char* hb   = (unsigned char*)p;
    unsigned char* obuf = hb;
    p += (size_t)NC * 1536;

    // ---- weight prep ----
    dim3 t768(768 / 32, 768 / 32);
    pack_fp8<<<t768, 256, 0, stream>>>(wq, wqkvq, 768, 768);
    pack_fp8<<<t768, 256, 0, stream>>>(wk, wqkvq + DD, 768, 768);
    pack_fp8<<<t768, 256, 0, stream>>>(wv, wqkvq + 2 * DD, 768, 768);
    pack_fp8<<<t768, 256, 0, stream>>>(wo, woq, 768, 768);
    transpose_bf16<<<t768, 256, 0, stream>>>(relik_w1 + DD, wruT, 768, 768);
    transpose_bf16<<<t768, 256, 0, stream>>>(uni_w1 + DD, wruT + DD, 768, 768);
    transpose_bf16<<<t768, 256, 0, stream>>>(relik_w1, relikAT, 768, 768);
    transpose_bf16<<<t768, 256, 0, stream>>>(uni_w1, uniAT, 768, 768);
    pack_fp8<<<dim3(3072 / 32, 768 / 32), 256, 0, stream>>>(ffn_w1, w1q, 768, 3072);
    pack_fp8<<<dim3(768 / 32, 3072 / 32), 256, 0, stream>>>(ffn_w2, w2q, 3072, 768);
    pack_bias<<<3, 256, 0, stream>>>(bq, bk, bv, bqkv);
    w2bar_kernel<<<D_DIM + 1, 256, 0, stream>>>(uni_w2, uni_b2, w2bar, b2bar);
    cvt_cand<<<(MK_CNT * D_DIM / 4 + 255) / 256, 256, 0, stream>>>(cand, candb, candq, MK_CNT * D_DIM / 4);

    // ---- per-mention precompute ----
    spans_kernel<<<M_CNT, 256, 0, stream>>>(text, starts, lens, mention, mentionq, mentionb, ctxb);
    launch_fp8_t<2, 0, 0>(mentionq, wqkvq, bqkv, qkvm, nullptr, M_CNT, 768, 2304, stream);
    launch_gemm(mentionb, relikAT, relik_b1, Ar, M_CNT, 768, 768, false, false, stream);
    launch_gemm(ctxb, uniAT, uni_b1, Au, M_CNT, 768, 768, false, false, stream);

    int nch = MK_CNT / NC;
    for (int c = 0; c < nch; ++c) {
        int g0 = c * NC;
        launch_fp8_t<2, 0, 0>(candq + (size_t)g0 * D_DIM, wqkvq, bqkv, qkvcb, nullptr, NC, 768, 2304, stream);
        launch_gemm(candb + (size_t)g0 * D_DIM, wruT, nullptr, rucb, NC, 768, 1536, false, true, stream);

        attn_kernel<<<NC, 512, 0, stream>>>(qkvm, qkvcb, obuf, g0);

        launch_fp8_t<2, 0, 0>(obuf, woq, bo, x1pre, nullptr, 2 * NC, 768, 768, stream);
        ln1_kernel<<<2 * NC / 4, 256, 0, stream>>>(x1pre, mention, candb,
                                                   ln1_g, ln1_b, x1f, x1q, g0);

        launch_fp8_t<1, 1, 0>(x1q, w1q, ffn_b1, hb, nullptr, 2 * NC, 768, 3072, stream);
        // FFN2 with fused +x1 residual -> x2f holds LN2 input
        launch_fp8_t<2, 0, 1>(hb, w2q, ffn_b2, x2f, x1f, 2 * NC, 3072, 768, stream);

        heads_kernel<<<NC / 4, 256, 0, stream>>>(x2f, ln2_g, ln2_b, Ar, Au, rucb,
                                                 relik_w2, relik_b2, w2bar, b2bar, out, g0);
    }
}